// Round 15
// baseline (472.043 us; speedup 1.0000x reference)
//
#include <hip/hip_runtime.h>
#include <hip/hip_bf16.h>
#include <stdint.h>

#define B_  2
#define S_  4096
#define D_  1024
#define FF_ 4096
#define E_  8
#define C_  1024

typedef unsigned short u16;
typedef unsigned int   u32;
typedef float f32x4  __attribute__((ext_vector_type(4)));
typedef short bf16x8 __attribute__((ext_vector_type(8)));
typedef u16   u16x8  __attribute__((ext_vector_type(8)));

static __device__ __forceinline__ u16 f2bf(float f) {
    union { float f; u32 u; } v; v.f = f;
    u32 u = v.u;
    u32 r = (u + 0x7FFFu + ((u >> 16) & 1u)) >> 16;  // RNE; inputs are finite
    return (u16)r;
}

static __device__ __forceinline__ void gload_lds16(const u16* g, u16* l) {
    __builtin_amdgcn_global_load_lds(
        (const __attribute__((address_space(1))) u32*)g,
        (__attribute__((address_space(3))) u32*)l, 16, 0, 0);
}

#define BAR()    asm volatile("s_barrier" ::: "memory")
#define WAITV(n) asm volatile("s_waitcnt vmcnt(" #n ")" ::: "memory")
#define WAITL0() do { asm volatile("s_waitcnt lgkmcnt(0)" ::: "memory"); \
                      __builtin_amdgcn_sched_barrier(0); } while (0)

// ============ merged transpose+convert: all of w1,w3 ([1024][4096]) and w2 ([4096][1024])
// fp32 [K][N] -> bf16 [N][K], one launch. Per block: 64n x 128k (two 64k halves pipelined
// through 2 LDS buffers: half1 loads issue under half0 store phase). 12288 blocks.
__global__ __launch_bounds__(256) void transpose_cvt_all(
    const float* __restrict__ w1, const float* __restrict__ w3,
    const float* __restrict__ w2,
    u16* __restrict__ w1t, u16* __restrict__ w3t, u16* __restrict__ w2t) {
    __shared__ u16 tb2[2][64 * 64];   // 16 KB
    int tb = blockIdx.x & 511, m = blockIdx.x >> 9;   // m: 0..23
    const float* s; u16* d; int K, N, n0, k00;
    if (m < 16) {
        K = D_; N = FF_;
        s = (m < 8 ? w1 : w3) + (size_t)(m & 7) * D_ * FF_;
        d = (m < 8 ? w1t : w3t) + (size_t)(m & 7) * D_ * FF_;
        n0 = (tb & 63) * 64; k00 = (tb >> 6) * 128;    // 64 n-tiles x 8 k-pairs
    } else {
        K = FF_; N = D_;
        s = w2 + (size_t)(m & 7) * FF_ * D_;
        d = w2t + (size_t)(m & 7) * FF_ * D_;
        n0 = (tb & 15) * 64; k00 = (tb >> 4) * 128;    // 16 n-tiles x 32 k-pairs
    }
    int lx = threadIdx.x & 63, wv = threadIdx.x >> 6;

#define TLOAD(V, k0) \
    _Pragma("unroll") for (int p = 0; p < 2; ++p) { \
        int k = p * 32 + wv * 8 + ((lx >> 4) << 1); \
        int n = (lx & 15) * 4; \
        V[p][0] = *(const float4*)&s[(size_t)((k0) + k) * N + n0 + n]; \
        V[p][1] = *(const float4*)&s[(size_t)((k0) + k + 1) * N + n0 + n]; }

#define TCONV(V, buf) \
    _Pragma("unroll") for (int p = 0; p < 2; ++p) { \
        int k = p * 32 + wv * 8 + ((lx >> 4) << 1); \
        int n = (lx & 15) * 4; \
        float x0[4] = {V[p][0].x, V[p][0].y, V[p][0].z, V[p][0].w}; \
        float x1[4] = {V[p][1].x, V[p][1].y, V[p][1].z, V[p][1].w}; \
        _Pragma("unroll") for (int j = 0; j < 4; ++j) { \
            int nn = n + j; \
            u32 pk = (u32)f2bf(x0[j]) | ((u32)f2bf(x1[j]) << 16); \
            int slot = (k >> 3) ^ ((nn & 7) ^ ((nn >> 3) & 7)); \
            *(u32*)((char*)tb2[buf] + nn * 128 + slot * 16 + (k & 7) * 2) = pk; } }

#define TSTORE(buf, k0) \
    _Pragma("unroll") for (int p = 0; p < 2; ++p) { \
        int n = p * 32 + (threadIdx.x >> 3); \
        int k8 = threadIdx.x & 7; \
        int slot = k8 ^ ((n & 7) ^ ((n >> 3) & 7)); \
        u16x8 vv = *(u16x8*)((char*)tb2[buf] + n * 128 + slot * 16); \
        *(u16x8*)&d[(size_t)(n0 + n) * K + (k0) + k8 * 8] = vv; }

    float4 vA[2][2], vB[2][2];
    TLOAD(vA, k00);
    TCONV(vA, 0);
    __syncthreads();
    TLOAD(vB, k00 + 64);    // issue half1 loads early: latency hides under half0 stores
    TSTORE(0, k00);
    TCONV(vB, 1);           // waits on half1 loads (overlapped with stores above)
    __syncthreads();
    TSTORE(1, k00 + 64);

#undef TLOAD
#undef TCONV
#undef TSTORE
}

// ============ router: logits (fp64 accum), argmax, max softmax prob; fused bf16 cvt ============
__global__ __launch_bounds__(256) void router_kernel(const float* __restrict__ hidden,
                                                     const float* __restrict__ gate_w,
                                                     float* __restrict__ logits_out,
                                                     int* __restrict__ sel,
                                                     float* __restrict__ maxp,
                                                     u16* __restrict__ xbf) {
    __shared__ float gw[D_ * E_];   // 32 KB
    for (int i = threadIdx.x; i < D_ * E_ / 4; i += 256)
        ((float4*)gw)[i] = ((const float4*)gate_w)[i];
    __syncthreads();

    int wave = threadIdx.x >> 6, lane = threadIdx.x & 63;
    int tok = blockIdx.x * 4 + wave;              // [0, B*S)
    const float* hrow = hidden + (size_t)tok * D_;
    u16* xrow = xbf + (size_t)tok * D_;

    double acc[8] = {0, 0, 0, 0, 0, 0, 0, 0};
#pragma unroll 4
    for (int i = 0; i < D_ / 64; i++) {
        int d = i * 64 + lane;
        float h = hrow[d];
        xrow[d] = f2bf(h);
        const float4* g4 = (const float4*)(gw + d * 8);
        float4 g0 = g4[0], g1 = g4[1];
        acc[0] += (double)h * g0.x; acc[1] += (double)h * g0.y;
        acc[2] += (double)h * g0.z; acc[3] += (double)h * g0.w;
        acc[4] += (double)h * g1.x; acc[5] += (double)h * g1.y;
        acc[6] += (double)h * g1.z; acc[7] += (double)h * g1.w;
    }
#pragma unroll
    for (int off = 32; off > 0; off >>= 1)
#pragma unroll
        for (int e = 0; e < 8; e++)
            acc[e] += __shfl_xor(acc[e], off);

    float l[8];
#pragma unroll
    for (int e = 0; e < 8; e++) l[e] = (float)acc[e];
    if (lane < 8) logits_out[(size_t)tok * 8 + lane] = l[lane];

    int am = 0; float mx = l[0];
#pragma unroll
    for (int e = 1; e < 8; e++) if (l[e] > mx) { mx = l[e]; am = e; }
    float sum = 0.f;
#pragma unroll
    for (int e = 0; e < 8; e++) sum += expf(l[e] - mx);
    if (lane == 0) { sel[tok] = am; maxp[tok] = 1.0f / sum; }
}

// ============ routing scan: hierarchical (histogram -> prefix -> assign), 1 block/batch ============
__global__ __launch_bounds__(1024) void scan_kernel(const int* __restrict__ sel,
                                                    int* __restrict__ pos,
                                                    int* __restrict__ slot_token,
                                                    int* __restrict__ counts) {
    __shared__ int hist[16][8];
    __shared__ int base[16][8];
    int b = blockIdx.x;
    int tid = threadIdx.x, wv = tid >> 6, l = tid & 63;
    unsigned long long below = (l == 0) ? 0ull : ((~0ull) >> (64 - l));
    const int* sb = sel + b * S_;

    int eloc[4];
    int cnt[8] = {0, 0, 0, 0, 0, 0, 0, 0};
#pragma unroll
    for (int c = 0; c < 4; c++) {
        int s = wv * 256 + c * 64 + l;
        int e = sb[s];
        eloc[c] = e;
#pragma unroll
        for (int ex = 0; ex < 8; ex++)
            cnt[ex] += (int)__popcll(__ballot(e == ex));
    }
    if (l == 0)
#pragma unroll
        for (int ex = 0; ex < 8; ex++) hist[wv][ex] = cnt[ex];
    __syncthreads();
    if (tid < 128) {
        int ex = tid & 7, v = tid >> 3;
        int s = 0;
        for (int w2 = 0; w2 < v; w2++) s += hist[w2][ex];
        base[v][ex] = s;
        if (v == 15) {
            int tot = s + hist[15][ex];
            counts[b * 8 + ex] = tot < C_ ? tot : C_;
        }
    }
    __syncthreads();
    int carry[8];
#pragma unroll
    for (int ex = 0; ex < 8; ex++) carry[ex] = base[wv][ex];
#pragma unroll
    for (int c = 0; c < 4; c++) {
        int s = wv * 256 + c * 64 + l;
        int e = eloc[c];
        int p = 0;
#pragma unroll
        for (int ex = 0; ex < 8; ex++) {
            unsigned long long m = __ballot(e == ex);
            if (e == ex) p = carry[ex] + (int)__popcll(m & below);
            carry[ex] += (int)__popcll(m);
        }
        pos[b * S_ + s] = p;
        if (p < C_) slot_token[(b * E_ + e) * C_ + p] = s;
    }
}

// ============ GEMM1: h = silu(x@w1) * (x@w3) — frozen best (R5/R14 bench: 218 us) ============
// tile 256(M slots, slot_token-indexed) x 128(N per panel). K-step=32, 4-slot LDS rotation,
// prefetch depth 3, 8 waves (2M x 4N). Sub-phases: per step, 2x {reads || stage-half ->
// lgkm(0) -> setprio(1) 16 MFMA} with one mid-step barrier. vmcnt never 0 mid-loop.
__global__ __launch_bounds__(512, 2) void gemm1_kernel(const u16* __restrict__ x,
                                                       const u16* __restrict__ w1t,
                                                       const u16* __restrict__ w3t,
                                                       const int* __restrict__ slot_token,
                                                       const int* __restrict__ counts,
                                                       u16* __restrict__ hbuf) {
    extern __shared__ u16 lds[];   // 4 * 16384 u16 = 128 KB
    // bijective XCD chunk swizzle (nwg = 2048, q = 256)
    int phys = blockIdx.x + 32 * (blockIdx.y + 4 * blockIdx.z);
    int virt = (phys & 7) * 256 + (phys >> 3);
    int bx = virt & 31, by = (virt >> 5) & 3, bz = virt >> 7;

    int z = bz;
    int cnt = counts[z];
    int c0 = by * 256;
    if (c0 >= cnt) return;
    int n0 = bx * 128;
    int b = z >> 3, e = z & 7;

    int tid = threadIdx.x, w = tid >> 6, l = tid & 63;
    int wm = w >> 2, wn = w & 3;

    // staging: thread writes phys chunk (tid&3) of row (tid>>2); source k-chunk inverse-swizzled
    int arow0 = tid >> 2, arow1 = arow0 + 128;
    int lk = ((tid & 3) ^ ((tid >> 3) & 3)) * 8;   // (row>>1)&3 identical for row and row+128
    int as0 = c0 + arow0, as1 = c0 + arow1;
    int tok0 = slot_token[z * C_ + (as0 < cnt ? as0 : 0)];
    int tok1 = slot_token[z * C_ + (as1 < cnt ? as1 : 0)];
    const u16* pA0 = x + ((size_t)(b * S_ + tok0)) * D_ + lk;
    const u16* pA1 = x + ((size_t)(b * S_ + tok1)) * D_ + lk;
    const u16* pB1 = w1t + ((size_t)e * FF_ + n0 + arow0) * D_ + lk;
    const u16* pB3 = w3t + ((size_t)e * FF_ + n0 + arow0) * D_ + lk;
    u32 wA0 = (u32)tid * 8, wA1 = (u32)tid * 8 + 4096;
    u32 wB1 = 8192 + (u32)tid * 8, wB3 = 12288 + (u32)tid * 8;

    u32 ck  = (u32)(((l >> 4) ^ ((l >> 1) & 3)) * 8);
    u32 aoff  = (u32)(wm * 128 + (l & 15)) * 32 + ck;                 // + f*512
    u32 b1off = 8192  + (u32)(wn * 32 + (l & 15)) * 32 + ck;          // + n*512
    u32 b3off = 12288 + (u32)(wn * 32 + (l & 15)) * 32 + ck;

    auto STAGE_A = [&](int t) {
        u16* Ls = lds + ((t & 3) << 14);
        int ko = t << 5;
        gload_lds16(pA0 + ko, Ls + wA0);
        gload_lds16(pA1 + ko, Ls + wA1);
    };
    auto STAGE_B = [&](int t) {
        u16* Ls = lds + ((t & 3) << 14);
        int ko = t << 5;
        gload_lds16(pB1 + ko, Ls + wB1);
        gload_lds16(pB3 + ko, Ls + wB3);
    };

    f32x4 acc1[8][2] = {};
    f32x4 acc3[8][2] = {};

    constexpr int NK = D_ / 32;  // 32
    STAGE_A(0); STAGE_B(0); STAGE_A(1); STAGE_B(1); STAGE_A(2); STAGE_B(2);
    for (int t = 0; t < NK; ++t) {
        if (t + 2 < NK)      { WAITV(8); }
        else if (t + 1 < NK) { WAITV(4); }
        else                 { WAITV(0); }
        BAR();
        const u16* Ls = lds + ((t & 3) << 14);
        // ---- sub-phase 0: af0..3 + all B frags; stage A-half of t+3 ----
        bf16x8 af[8], b1f[2], b3f[2];
#pragma unroll
        for (int f = 0; f < 4; f++) af[f] = *(const bf16x8*)(Ls + aoff + f * 512);
#pragma unroll
        for (int n = 0; n < 2; n++) {
            b1f[n] = *(const bf16x8*)(Ls + b1off + n * 512);
            b3f[n] = *(const bf16x8*)(Ls + b3off + n * 512);
        }
        if (t + 3 < NK) STAGE_A(t + 3);
        WAITL0();
        __builtin_amdgcn_s_setprio(1);
#pragma unroll
        for (int f = 0; f < 4; f++)
#pragma unroll
            for (int n = 0; n < 2; n++) {
                acc1[f][n] = __builtin_amdgcn_mfma_f32_16x16x32_bf16(af[f], b1f[n], acc1[f][n], 0, 0, 0);
                acc3[f][n] = __builtin_amdgcn_mfma_f32_16x16x32_bf16(af[f], b3f[n], acc3[f][n], 0, 0, 0);
            }
        __builtin_amdgcn_s_setprio(0);
        BAR();
        // ---- sub-phase 1: af4..7; stage B-half of t+3 ----
#pragma unroll
        for (int f = 4; f < 8; f++) af[f] = *(const bf16x8*)(Ls + aoff + f * 512);
        if (t + 3 < NK) STAGE_B(t + 3);
        WAITL0();
        __builtin_amdgcn_s_setprio(1);
#pragma unroll
        for (int f = 4; f < 8; f++)
#pragma unroll
            for (int n = 0; n < 2; n++) {
                acc1[f][n] = __builtin_amdgcn_mfma_f32_16x16x32_bf16(af[f], b1f[n], acc1[f][n], 0, 0, 0);
                acc3[f][n] = __builtin_amdgcn_mfma_f32_16x16x32_bf16(af[f], b3f[n], acc3[f][n], 0, 0, 0);
            }
        __builtin_amdgcn_s_setprio(0);
    }

#pragma unroll
    for (int f = 0; f < 8; f++) {
        int row = wm * 128 + f * 16 + ((l >> 4) << 2);
#pragma unroll
        for (int rr = 0; rr < 4; rr++) {
            int slot = c0 + row + rr;
            if (slot < cnt) {
                size_t base = ((size_t)z * C_ + slot) * FF_ + n0 + wn * 32 + (l & 15);
#pragma unroll
                for (int n = 0; n < 2; n++) {
                    float g = acc1[f][n][rr], uu = acc3[f][n][rr];
                    float h = (g / (1.f + __expf(-g))) * uu;
                    hbuf[base + n * 16] = f2bf(h);
                }
            }
        }
    }
}

// ============ GEMM2: out[token] = maxp * (h @ w2), scatter epilogue — frozen ============
// tile 256(M) x 256(N). K-step=32, 4-slot rotation, depth 3, 8 waves (2M x 4N),
// 2-sub-phase schedule.
__global__ __launch_bounds__(512, 2) void gemm2_kernel(const u16* __restrict__ hbuf,
                                                       const u16* __restrict__ w2t,
                                                       const int* __restrict__ slot_token,
                                                       const int* __restrict__ counts,
                                                       const float* __restrict__ maxp,
                                                       float* __restrict__ out) {
    extern __shared__ u16 lds[];   // 128 KB
    // bijective XCD chunk swizzle (nwg = 256, q = 32)
    int phys = blockIdx.x + 4 * (blockIdx.y + 4 * blockIdx.z);
    int virt = (phys & 7) * 32 + (phys >> 3);
    int bx = virt & 3, by = (virt >> 2) & 3, bz = virt >> 4;

    int z = bz;
    int cnt = counts[z];
    int c0 = by * 256;
    if (c0 >= cnt) return;
    int n0 = bx * 256;
    int b = z >> 3, e = z & 7;

    int tid = threadIdx.x, w = tid >> 6, l = tid & 63;
    int wm = w >> 2, wn = w & 3;

    int arow0 = tid >> 2;
    int lk = ((tid & 3) ^ ((tid >> 3) & 3)) * 8;
    const u16* pA0 = hbuf + ((size_t)z * C_ + c0 + arow0) * FF_ + lk;
    const u16* pA1 = pA0 + (size_t)128 * FF_;
    const u16* pB0 = w2t + ((size_t)e * D_ + n0 + arow0) * FF_ + lk;
    const u16* pB1 = pB0 + (size_t)128 * FF_;
    u32 wsl = (u32)tid * 8;

    u32 ck  = (u32)(((l >> 4) ^ ((l >> 1) & 3)) * 8);
    u32 aoff = (u32)(wm * 128 + (l & 15)) * 32 + ck;                 // + f*512
    u32 boff = 8192 + (u32)(wn * 64 + (l & 15)) * 32 + ck;           // + n*512

    auto STAGE_A = [&](int t) {
        u16* Ls = lds + ((t & 3) << 14);
        int ko = t << 5;
        gload_lds16(pA0 + ko, Ls + wsl);
        gload_lds16(pA1 + ko, Ls + 4096 + wsl);
    };
    auto STAGE_B = [&](int t) {
        u16* Ls = lds + ((t & 3) << 14);
        int ko = t << 5;
        gload_lds16(pB0 + ko, Ls + 8192 + wsl);
        gload_lds16(pB1 + ko, Ls + 12288 + wsl);
    };

    f32x4 acc[8][4] = {};

    constexpr int NK = FF_ / 32;  // 128
    STAGE_A(0); STAGE_B(0); STAGE_A(1); STAGE_B(1); STAGE_A(2); STAGE_B(2);
    for (int t = 0; t < NK; ++t) {
        if (t + 2 < NK)      { WAITV(8); }
        else if (t + 1 < NK) { WAITV(4); }
        else                 { WAITV(0); }
        BAR();
        const u16* Ls = lds + ((t & 3) << 14);
        bf16x8 af[8], bfv[4];
#pragma unroll
        for (int f = 0; f < 4; f++) af[f] = *(const bf16x8*)(Ls + aoff + f * 512);
#pragma unroll
        for (int n = 0; n < 4; n++) bfv[n] = *(const bf16x8*)(Ls + boff + n * 512);
        if (t + 3 < NK) STAGE_A(t + 3);
        WAITL0();
        __builtin_amdgcn_s_setprio(1);
#pragma unroll
        for (int f = 0; f < 4; f++)
#pragma unroll
            for (int n = 0; n < 4; n++)
                acc[f][n] = __builtin_amdgcn_mfma_f32_16x16x32_bf16(af[f], bfv[n], acc[f][n], 0, 0, 0);
        __builtin_amdgcn_s_setprio(0);
        BAR();
#pragma unroll
        for (int f = 4; f < 8; f++) af[f] = *(const bf16x8*)(Ls + aoff + f * 512);
        if (t + 3 < NK) STAGE_B(t + 3);
        WAITL0();
        __builtin_amdgcn_s_setprio(1);
#pragma unroll
        for (int f = 4; f < 8; f++)
#pragma unroll
            for (int n = 0; n < 4; n++)
                acc[f][n] = __builtin_amdgcn_mfma_f32_16x16x32_bf16(af[f], bfv[n], acc[f][n], 0, 0, 0);
        __builtin_amdgcn_s_setprio(0);
    }

#pragma unroll
    for (int f = 0; f < 8; f++) {
        int row = wm * 128 + f * 16 + ((l >> 4) << 2);
#pragma unroll
        for (int rr = 0; rr < 4; rr++) {
            int slot = c0 + row + rr;
            if (slot < cnt) {
                int s = slot_token[z * C_ + slot];
                float sc = maxp[b * S_ + s];
                float* orow = out + ((size_t)b * S_ + s) * D_ + n0 + wn * 64 + (l & 15);
#pragma unroll
                for (int n = 0; n < 4; n++)
                    orow[n * 16] = sc * acc[f][n][rr];
            }
        }
    }
}

// ============ dropped tokens keep hidden (rare; usually no-op) — grid-stride ============
__global__ __launch_bounds__(256) void combine_dropped(const float* __restrict__ hidden,
                                                       const int* __restrict__ pos,
                                                       const float* __restrict__ maxp,
                                                       float* __restrict__ out) {
    for (int t = blockIdx.x; t < B_ * S_; t += gridDim.x) {
        if (pos[t] < C_) continue;
        float sc = maxp[t];
        const float* src = hidden + (size_t)t * D_;
        float* dst = out + (size_t)t * D_;
        for (int d = threadIdx.x; d < D_; d += 256) dst[d] = sc * src[d];
    }
}

extern "C" void kernel_launch(void* const* d_in, const int* in_sizes, int n_in,
                              void* d_out, int out_size, void* d_ws, size_t ws_size,
                              hipStream_t stream) {
    const float* hidden = (const float*)d_in[0];
    const float* gate_w = (const float*)d_in[1];
    const float* w1     = (const float*)d_in[2];
    const float* w2     = (const float*)d_in[3];
    const float* w3     = (const float*)d_in[4];

    float* out        = (float*)d_out;
    float* logits_out = out + (size_t)B_ * S_ * D_;

    char* ws = (char*)d_ws;
    u16* hidden_bf = (u16*)ws;            ws += (size_t)B_ * S_ * D_ * 2;
    u16* w1t       = (u16*)ws;            ws += (size_t)E_ * D_ * FF_ * 2;
    u16* w3t       = (u16*)ws;            ws += (size_t)E_ * D_ * FF_ * 2;
    u16* w2t       = (u16*)ws;            ws += (size_t)E_ * D_ * FF_ * 2;
    u16* hbuf      = (u16*)ws;            ws += (size_t)B_ * E_ * C_ * FF_ * 2;
    int*   sel        = (int*)ws;         ws += (size_t)B_ * S_ * 4;
    int*   pos        = (int*)ws;         ws += (size_t)B_ * S_ * 4;
    float* maxp       = (float*)ws;       ws += (size_t)B_ * S_ * 4;
    int*   slot_token = (int*)ws;         ws += (size_t)B_ * E_ * C_ * 4;
    int*   counts     = (int*)ws;         ws += (size_t)B_ * E_ * 4;

    (void)hipFuncSetAttribute((const void*)gemm1_kernel,
                              hipFuncAttributeMaxDynamicSharedMemorySize, 131072);
    (void)hipFuncSetAttribute((const void*)gemm2_kernel,
                              hipFuncAttributeMaxDynamicSharedMemorySize, 131072);

    router_kernel<<<B_ * S_ / 4, 256, 0, stream>>>(hidden, gate_w, logits_out, sel, maxp, hidden_bf);
    scan_kernel<<<B_, 1024, 0, stream>>>(sel, pos, slot_token, counts);

    transpose_cvt_all<<<24 * 512, 256, 0, stream>>>(w1, w3, w2, w1t, w3t, w2t);

    gemm1_kernel<<<dim3(32, 4, 16), 512, 131072, stream>>>(hidden_bf, w1t, w3t, slot_token, counts, hbuf);
    gemm2_kernel<<<dim3(4, 4, 16), 512, 131072, stream>>>(hbuf, w2t, slot_token, counts, maxp, out);
    combine_dropped<<<256, 256, 0, stream>>>(hidden, pos, maxp, out);
}